// Round 10
// baseline (362.893 us; speedup 1.0000x reference)
//
#include <hip/hip_runtime.h>
#include <hip/hip_bf16.h>
#include <stdint.h>

#define Bv 128
#define Hv 256
#define INv 19
#define Pv 512
#define Cv 1024
#define NLh 7

typedef __attribute__((ext_vector_type(4))) float floatx4;
typedef __attribute__((ext_vector_type(8))) short shortx8;
typedef __attribute__((ext_vector_type(4))) unsigned int uintx4;

// single-instruction packed fp32->bf16 (RNE), lo -> low 16, hi -> high 16
__device__ __forceinline__ unsigned int cvt_pk_bf16(float lo, float hi) {
    unsigned int r;
    asm("v_cvt_pk_bf16_f32 %0, %1, %2" : "=v"(r) : "v"(lo), "v"(hi));
    return r;
}

__device__ __forceinline__ int swz(int r) { return ((r & 7) ^ ((r >> 3) & 7)); }

// LDS-only barrier: waits own DS ops, leaves global prefetch loads in flight. [T4]
#define BAR() do { asm volatile("s_waitcnt lgkmcnt(0)" ::: "memory"); \
                   __builtin_amdgcn_s_barrier(); } while (0)

// ---------------- fused MLP: first + 7 hidden layers, one launch ----------------
__global__ __launch_bounds__(256) void mlp_fused(
    const float* __restrict__ pos, const float* __restrict__ ue,
    const float* __restrict__ bs,  const float* __restrict__ addf,
    const float* __restrict__ attW1, const float* __restrict__ attb1,
    const float* __restrict__ attWh, const float* __restrict__ attbh,
    const float* __restrict__ radW1, const float* __restrict__ radb1,
    const float* __restrict__ radWh, const float* __restrict__ radbh,
    unsigned short* __restrict__ feat)   // bf16 [128][512]
{
    int blk = blockIdx.x;              // 128 blocks
    int net = blk >> 6, bq = blk & 63; // rows 2bq, 2bq+1
    const float* W1 = net ? radW1 : attW1;
    const float* b1 = net ? radb1 : attb1;
    const float* Wh = net ? radWh : attWh;
    const float* bh = net ? radbh : attbh;
    __shared__ float xs[2][INv];
    __shared__ float hr[2][Hv];
    __shared__ float part[4][2][Hv];
    int t = threadIdx.x;
    if (t < 2 * INv) {
        int r = t / INv, k = t - r * INv;
        int b = bq * 2 + r;
        float v;
        if (k < 3) v = pos[b*3 + k];
        else if (k < 5) v = ue[b*2 + (k-3)];
        else if (k < 9) v = bs[b*4 + (k-5)];
        else v = addf[b*10 + (k-9)];
        xs[r][k] = v;
    }
    __syncthreads();
    {
        float a0 = b1[t], a1 = a0;
        #pragma unroll
        for (int k = 0; k < INv; ++k) {
            float w = W1[k*Hv + t];
            a0 += xs[0][k] * w;
            a1 += xs[1][k] * w;
        }
        hr[0][t] = fmaxf(a0, 0.f);
        hr[1][t] = fmaxf(a1, 0.f);
    }
    __syncthreads();
    int half = t >> 6, oq = t & 63;
    for (int layer = 0; layer < NLh; ++layer) {
        const float* W = Wh + (size_t)layer * Hv * Hv;
        const float* Wp = W + (size_t)(half * 64) * Hv + oq * 4;
        floatx4 a0r0 = {0.f,0.f,0.f,0.f}, a1r0 = {0.f,0.f,0.f,0.f};
        floatx4 a0r1 = {0.f,0.f,0.f,0.f}, a1r1 = {0.f,0.f,0.f,0.f};
        #pragma unroll 8
        for (int kk = 0; kk < 64; kk += 2) {
            floatx4 w0 = *reinterpret_cast<const floatx4*>(Wp + (size_t)kk * Hv);
            floatx4 w1 = *reinterpret_cast<const floatx4*>(Wp + (size_t)(kk+1) * Hv);
            float h00 = hr[0][half*64 + kk], h01 = hr[0][half*64 + kk + 1];
            float h10 = hr[1][half*64 + kk], h11 = hr[1][half*64 + kk + 1];
            a0r0 += w0 * h00; a1r0 += w1 * h01;
            a0r1 += w0 * h10; a1r1 += w1 * h11;
        }
        floatx4 r0 = a0r0 + a1r0, r1 = a0r1 + a1r1;
        *reinterpret_cast<floatx4*>(&part[half][0][oq*4]) = r0;
        *reinterpret_cast<floatx4*>(&part[half][1][oq*4]) = r1;
        __syncthreads();
        int r = t >> 7, o2 = (t & 127) * 2;
        const float* bias = bh + layer * Hv;
        float s0 = part[0][r][o2]   + part[1][r][o2]   + part[2][r][o2]   + part[3][r][o2]   + bias[o2];
        float s1 = part[0][r][o2+1] + part[1][r][o2+1] + part[2][r][o2+1] + part[3][r][o2+1] + bias[o2+1];
        s0 = fmaxf(s0, 0.f); s1 = fmaxf(s1, 0.f);
        if (layer == NLh - 1) {
            *reinterpret_cast<unsigned int*>(
                feat + (size_t)(bq*2 + r) * Pv + net*Hv + o2) = cvt_pk_bf16(s0, s1);
        } else {
            hr[r][o2] = s0; hr[r][o2+1] = s1;
        }
        __syncthreads();
    }
}

// ---------------- Prism helpers ----------------

__device__ __forceinline__ void stage_w_p(const float* __restrict__ src,
                                          int kg, int oq, floatx4* r) {
    const float* p = src + (size_t)(kg * 8) * Hv + oq * 4;
    #pragma unroll
    for (int i = 0; i < 8; ++i) r[i] = *reinterpret_cast<const floatx4*>(p + i * Hv);
}

// transpose 8k x 4o in regs -> 4 swizzled ds_write_b128 (cvt_pk: 4 VALU per write)
__device__ __forceinline__ void write_w(char* wb, int kg, int oq, const floatx4* r) {
    #pragma unroll
    for (int j = 0; j < 4; ++j) {
        int o = oq*4 + j;
        uintx4 v = { cvt_pk_bf16(r[0][j], r[1][j]),
                     cvt_pk_bf16(r[2][j], r[3][j]),
                     cvt_pk_bf16(r[4][j], r[5][j]),
                     cvt_pk_bf16(r[6][j], r[7][j]) };
        int slot = kg ^ swz(o);
        *reinterpret_cast<uintx4*>(wb + o*128 + slot*16) = v;
    }
}

// stage feat bf16 chunk t: [128 rows][64 k] -> 2 uintx4 per thread
__device__ __forceinline__ void stage_a(const unsigned short* __restrict__ feat,
                                        int t, int tid, uintx4* r) {
    #pragma unroll
    for (int q = 0; q < 2; ++q) {
        int si = tid + q*512, row = si >> 3, s = si & 7;
        r[q] = *reinterpret_cast<const uintx4*>(feat + row*Pv + t*64 + s*8);
    }
}

__device__ __forceinline__ void write_a(char* ab, int tid, const uintx4* r) {
    #pragma unroll
    for (int q = 0; q < 2; ++q) {
        int si = tid + q*512, row = si >> 3, s = si & 7;
        int slot = s ^ swz(row);
        *reinterpret_cast<uintx4*>(ab + row*128 + slot*16) = r[q];
    }
}

__device__ __forceinline__ void mfma_l1(const char* ab, const char* wb,
                                        int wm, int wn, int l,
                                        floatx4 (&acc)[4][4]) {
    #pragma unroll
    for (int ks = 0; ks < 2; ++ks) {
        shortx8 af[4], bf[4];
        #pragma unroll
        for (int m = 0; m < 4; ++m) {
            int row = wm*64 + m*16 + (l & 15);
            int slot = (ks*4 + (l >> 4)) ^ swz(row);
            af[m] = *reinterpret_cast<const shortx8*>(ab + row*128 + slot*16);
        }
        #pragma unroll
        for (int n = 0; n < 4; ++n) {
            int o = wn*64 + n*16 + (l & 15);
            int slot = (ks*4 + (l >> 4)) ^ swz(o);
            bf[n] = *reinterpret_cast<const shortx8*>(wb + o*128 + slot*16);
        }
        #pragma unroll
        for (int m = 0; m < 4; ++m)
            #pragma unroll
            for (int n = 0; n < 4; ++n)
                acc[m][n] = __builtin_amdgcn_mfma_f32_16x16x32_bf16(af[m], bf[n], acc[m][n], 0, 0, 0);
    }
}

__device__ __forceinline__ void mfma_l2(const char* h1, const char* wb, int t2,
                                        int wm, int wn, int l,
                                        floatx4 (&acc)[4][4]) {
    #pragma unroll
    for (int ks = 0; ks < 2; ++ks) {
        shortx8 af[4], bf[4];
        #pragma unroll
        for (int m = 0; m < 4; ++m) {
            int row = wm*64 + m*16 + (l & 15);
            int k2 = t2*64 + ks*32 + (l >> 4)*8;
            af[m] = *reinterpret_cast<const shortx8*>(h1 + row*512 + ((k2*2) ^ (swz(row) << 4)));
        }
        #pragma unroll
        for (int n = 0; n < 4; ++n) {
            int o = wn*64 + n*16 + (l & 15);
            int slot = (ks*4 + (l >> 4)) ^ swz(o);
            bf[n] = *reinterpret_cast<const shortx8*>(wb + o*128 + slot*16);
        }
        #pragma unroll
        for (int m = 0; m < 4; ++m)
            #pragma unroll
            for (int n = 0; n < 4; ++n)
                acc[m][n] = __builtin_amdgcn_mfma_f32_16x16x32_bf16(af[m], bf[n], acc[m][n], 0, 0, 0);
    }
}

// ---------------- Prism: 2 subcarriers per block, depth-2 / dist-1 pipeline ----------------
// Best-measured r3 structure. Bridge across the c-boundary: during c0's L2 the
// free register sets stage A0/A1 + W2c2/3 + next-c W1 chunks 0/1 (A issued
// before W within each iter; every consume targets loads >=1 barrier old);
// after L3, two bridge writes (ab0, wb0) re-arm the pipeline for c1.

__global__ __launch_bounds__(512) void prism_kernel(
    const unsigned short* __restrict__ feat,
    const float* __restrict__ W1, const float* __restrict__ b1,
    const float* __restrict__ W2, const float* __restrict__ b2,
    const float* __restrict__ W3, const float* __restrict__ b3,
    float* __restrict__ out)
{
    __shared__ __align__(16) char smem[131072];
    char* ab0 = smem;                 // A ring: 2 x 16KB
    char* ab1 = smem + 16384;
    char* wb0 = smem + 32768;         // L1 W ring: 2 x 32KB
    char* wb1 = smem + 65536;
    char* h1  = smem;                 // 64KB bf16 [128][256] swizzled (over ab0,ab1,wb0)
    char* w2b0 = smem + 65536;        // L2 W ring (w2b0 == wb1 region; W1 dead)
    char* w2b1 = smem + 98304;
    float* subws = (float*)smem;      // [4][128] (over ab0 head; h1 dead at L3)

    const int tid = threadIdx.x;
    const int l = tid & 63;
    const int w = tid >> 6;
    const int wm = w >> 2;
    const int wn = w & 3;
    const int kg = w;
    const int oq = l;

    floatx4 wr[2][8];   // depth-2 W prefetch ring
    uintx4  ar[2][2];   // depth-2 A prefetch ring

    // ---- prologue (c0): W0,A0,W1,A1 in flight; write chunk 0 ----
    {
        const float* W1c = W1 + (size_t)(blockIdx.x * 2) * (Pv * Hv);
        stage_w_p(W1c + (size_t)0 * 64 * Hv, kg, oq, wr[0]);
        stage_a(feat, 0, tid, ar[0]);
        stage_w_p(W1c + (size_t)1 * 64 * Hv, kg, oq, wr[1]);
        stage_a(feat, 1, tid, ar[1]);
        write_w(wb0, kg, oq, wr[0]);
        write_a(ab0, tid, ar[0]);
        BAR();
    }

    for (int k = 0; k < 2; ++k) {
        const int c = blockIdx.x * 2 + k;
        const float* W1c = W1 + (size_t)c * (Pv * Hv);
        const float* W2c = W2 + (size_t)c * (Hv * Hv);
        const float* W1n = W1c + (size_t)(Pv * Hv);   // deref'd only when k==0

        floatx4 acc[4][4];
        #pragma unroll
        for (int m = 0; m < 4; ++m)
            #pragma unroll
            for (int n = 0; n < 4; ++n)
                acc[m][n] = (floatx4){0.f, 0.f, 0.f, 0.f};

        // ---- L1: 8 chunks; stage chunk t+2 into set t&1; write chunk t+1 (dist 1) ----
        #pragma unroll
        for (int t = 0; t < 8; ++t) {
            if (t + 2 < 8) {
                stage_w_p(W1c + (size_t)(t + 2) * 64 * Hv, kg, oq, wr[t & 1]);
                stage_a(feat, t + 2, tid, ar[t & 1]);
            } else if (t == 6) {
                stage_w_p(W2c + (size_t)0 * 64 * Hv, kg, oq, wr[0]);
            } else {  // t == 7
                stage_w_p(W2c + (size_t)1 * 64 * Hv, kg, oq, wr[1]);
            }
            mfma_l1((t & 1) ? ab1 : ab0, (t & 1) ? wb1 : wb0, wm, wn, l, acc);
            if (t + 1 < 8) {
                if ((t + 1) & 1) { write_w(wb1, kg, oq, wr[1]); write_a(ab1, tid, ar[1]); }
                else             { write_w(wb0, kg, oq, wr[0]); write_a(ab0, tid, ar[0]); }
            }
            BAR();
        }

        // ---- h1 epilogue: relu(acc+b1) -> LDS bf16 swizzled; write W2c0 buf ----
        {
            float bias1v[4];
            #pragma unroll
            for (int n = 0; n < 4; ++n)
                bias1v[n] = b1[c*Hv + wn*64 + n*16 + (l & 15)];
            #pragma unroll
            for (int m = 0; m < 4; ++m) {
                #pragma unroll
                for (int n = 0; n < 4; ++n) {
                    int o = wn*64 + n*16 + (l & 15);
                    #pragma unroll
                    for (int jj = 0; jj < 4; ++jj) {
                        int bb = wm*64 + m*16 + (l >> 4)*4 + jj;
                        float v = fmaxf(acc[m][n][jj] + bias1v[n], 0.f);
                        *(unsigned short*)(h1 + bb*512 + ((o*2) ^ (swz(bb) << 4))) =
                            (unsigned short)(cvt_pk_bf16(v, v) & 0xffffu);
                    }
                }
            }
        }
        write_w(w2b0, kg, oq, wr[0]);   // W2 chunk 0 (staged at L1 t=6)
        BAR();

        #pragma unroll
        for (int m = 0; m < 4; ++m)
            #pragma unroll
            for (int n = 0; n < 4; ++n)
                acc[m][n] = (floatx4){0.f, 0.f, 0.f, 0.f};

        // ---- L2: 4 chunks. k==0 additionally stages A0/A1 + next-c W1 0/1 ----
        #pragma unroll
        for (int t2 = 0; t2 < 4; ++t2) {
            if (t2 == 0) {
                if (k == 0) stage_a(feat, 0, tid, ar[0]);        // A first
                stage_w_p(W2c + (size_t)2 * 64 * Hv, kg, oq, wr[0]);
            } else if (t2 == 1) {
                if (k == 0) stage_a(feat, 1, tid, ar[1]);
                stage_w_p(W2c + (size_t)3 * 64 * Hv, kg, oq, wr[1]);
            } else if (t2 == 2) {
                if (k == 0) stage_w_p(W1n + (size_t)0 * 64 * Hv, kg, oq, wr[0]);
            } else {  // t2 == 3
                if (k == 0) stage_w_p(W1n + (size_t)1 * 64 * Hv, kg, oq, wr[1]);
            }
            mfma_l2(h1, (t2 & 1) ? w2b1 : w2b0, t2, wm, wn, l, acc);
            if (t2 == 0)      write_w(w2b1, kg, oq, wr[1]);  // W2c1 (L1 t=7)
            else if (t2 == 1) write_w(w2b0, kg, oq, wr[0]);  // W2c2
            else if (t2 == 2) write_w(w2b1, kg, oq, wr[1]);  // W2c3
            BAR();
        }

        // ---- L3: sub = relu(h2)·W3 + b3 ----
        float bias2v[4], w3v[4];
        #pragma unroll
        for (int n = 0; n < 4; ++n) {
            int o = wn*64 + n*16 + (l & 15);
            bias2v[n] = b2[c*Hv + o];
            w3v[n]    = W3[c*Hv + o];
        }
        float b3v = b3[c];
        float p[4][4];
        #pragma unroll
        for (int m = 0; m < 4; ++m)
            #pragma unroll
            for (int jj = 0; jj < 4; ++jj) {
                float s = 0.f;
                #pragma unroll
                for (int n = 0; n < 4; ++n)
                    s += fmaxf(acc[m][n][jj] + bias2v[n], 0.f) * w3v[n];
                p[m][jj] = s;
            }
        #pragma unroll
        for (int m = 0; m < 4; ++m)
            #pragma unroll
            for (int jj = 0; jj < 4; ++jj) {
                p[m][jj] += __shfl_xor(p[m][jj], 1, 64);
                p[m][jj] += __shfl_xor(p[m][jj], 2, 64);
                p[m][jj] += __shfl_xor(p[m][jj], 4, 64);
                p[m][jj] += __shfl_xor(p[m][jj], 8, 64);
            }
        BAR();   // all h1/w2 reads done before subws overwrite
        {
            int t16 = l & 15;
            float pv = 0.f;
            #pragma unroll
            for (int m = 0; m < 4; ++m)
                #pragma unroll
                for (int jj = 0; jj < 4; ++jj)
                    if (m == (t16 >> 2) && jj == (t16 & 3)) pv = p[m][jj];
            int bb = wm*64 + (t16 >> 2)*16 + (l >> 4)*4 + (t16 & 3);
            subws[wn*128 + bb] = pv;
        }
        BAR();
        if (tid < 128) {
            float s = subws[tid] + subws[128 + tid] + subws[256 + tid] + subws[384 + tid] + b3v;
            out[(size_t)tid * Cv + c] = s;
        }
        if (k == 0) {
            BAR();                        // subws reads done before ab0 overwrite
            write_a(ab0, tid, ar[0]);     // A0 (issued L2 t2=0)
            write_w(wb0, kg, oq, wr[0]);  // W1n chunk 0 (issued L2 t2=2)
            BAR();                        // c1's L1 t=0 reads ab0/wb0; ar[1]/wr[1]
        }                                 // still hold A1/W1n1 for its first write
    }
}

// ---------------- mimo epilogue ----------------

__global__ __launch_bounds__(256) void mimo_kernel(
    const float* __restrict__ sub, const float* __restrict__ mW,
    const float* __restrict__ mB, float* __restrict__ out)
{
    int b = blockIdx.x;
    int t = threadIdx.x;
    float s = 0.f;
    #pragma unroll
    for (int j = 0; j < 4; ++j) s += sub[b*Cv + t + j*256];
    #pragma unroll
    for (int m = 1; m < 64; m <<= 1) s += __shfl_xor(s, m, 64);
    __shared__ float red[4];
    if ((t & 63) == 0) red[t >> 6] = s;
    __syncthreads();
    if (t < 8) {
        float mean = (red[0] + red[1] + red[2] + red[3]) * (1.0f / 1024.0f);
        out[Bv * Cv + b*8 + t] = mean * mW[t] + mB[t];
    }
}

// ---------------- launch ----------------

extern "C" void kernel_launch(void* const* d_in, const int* in_sizes, int n_in,
                              void* d_out, int out_size, void* d_ws, size_t ws_size,
                              hipStream_t stream) {
    (void)in_sizes; (void)n_in; (void)out_size; (void)ws_size;
    const float* pos   = (const float*)d_in[0];
    const float* ue    = (const float*)d_in[1];
    const float* bsant = (const float*)d_in[2];
    const float* addf  = (const float*)d_in[3];
    const float* attW1 = (const float*)d_in[4];
    const float* attb1 = (const float*)d_in[5];
    const float* attWh = (const float*)d_in[6];
    const float* attbh = (const float*)d_in[7];
    const float* radW1 = (const float*)d_in[8];
    const float* radb1 = (const float*)d_in[9];
    const float* radWh = (const float*)d_in[10];
    const float* radbh = (const float*)d_in[11];
    const float* pW1   = (const float*)d_in[12];
    const float* pb1   = (const float*)d_in[13];
    const float* pW2   = (const float*)d_in[14];
    const float* pb2   = (const float*)d_in[15];
    const float* pW3   = (const float*)d_in[16];
    const float* pb3   = (const float*)d_in[17];
    const float* mW    = (const float*)d_in[18];
    const float* mB    = (const float*)d_in[19];
    float* out = (float*)d_out;

    unsigned short* feat = (unsigned short*)d_ws;   // [128][512] bf16

    mlp_fused<<<128, 256, 0, stream>>>(pos, ue, bsant, addf,
                                       attW1, attb1, attWh, attbh,
                                       radW1, radb1, radWh, radbh, feat);
    prism_kernel<<<Cv / 2, 512, 0, stream>>>(feat, pW1, pb1, pW2, pb2, pW3, pb3, out);
    mimo_kernel<<<Bv, 256, 0, stream>>>(out, mW, mB, out);
}

// Round 11
// 225.923 us; speedup vs baseline: 1.6063x; 1.6063x over previous
//
#include <hip/hip_runtime.h>
#include <hip/hip_bf16.h>
#include <stdint.h>

#define Bv 128
#define Hv 256
#define INv 19
#define Pv 512
#define Cv 1024
#define NLh 7
#define CH 32

typedef __attribute__((ext_vector_type(4))) float floatx4;
typedef __attribute__((ext_vector_type(8))) short shortx8;
typedef __attribute__((ext_vector_type(4))) unsigned int uintx4;

// packed fp32->bf16 (RNE): lo -> bits[15:0], hi -> bits[31:16]
__device__ __forceinline__ unsigned int cvt_pk_bf16(float lo, float hi) {
    unsigned int r;
    asm("v_cvt_pk_bf16_f32 %0, %1, %2" : "=v"(r) : "v"(lo), "v"(hi));
    return r;
}

__device__ __forceinline__ int swz(int r) { return ((r & 7) ^ ((r >> 3) & 7)); }

// ---------------- fused MLP: first + 7 hidden layers, one launch ----------------
__global__ __launch_bounds__(256) void mlp_fused(
    const float* __restrict__ pos, const float* __restrict__ ue,
    const float* __restrict__ bs,  const float* __restrict__ addf,
    const float* __restrict__ attW1, const float* __restrict__ attb1,
    const float* __restrict__ attWh, const float* __restrict__ attbh,
    const float* __restrict__ radW1, const float* __restrict__ radb1,
    const float* __restrict__ radWh, const float* __restrict__ radbh,
    unsigned short* __restrict__ feat)   // bf16 [128][512]
{
    int blk = blockIdx.x;              // 128 blocks
    int net = blk >> 6, bq = blk & 63; // rows 2bq, 2bq+1
    const float* W1 = net ? radW1 : attW1;
    const float* b1 = net ? radb1 : attb1;
    const float* Wh = net ? radWh : attWh;
    const float* bh = net ? radbh : attbh;
    __shared__ float xs[2][INv];
    __shared__ float hr[2][Hv];
    __shared__ float part[4][2][Hv];
    int t = threadIdx.x;
    if (t < 2 * INv) {
        int r = t / INv, k = t - r * INv;
        int b = bq * 2 + r;
        float v;
        if (k < 3) v = pos[b*3 + k];
        else if (k < 5) v = ue[b*2 + (k-3)];
        else if (k < 9) v = bs[b*4 + (k-5)];
        else v = addf[b*10 + (k-9)];
        xs[r][k] = v;
    }
    __syncthreads();
    {
        float a0 = b1[t], a1 = a0;
        #pragma unroll
        for (int k = 0; k < INv; ++k) {
            float w = W1[k*Hv + t];
            a0 += xs[0][k] * w;
            a1 += xs[1][k] * w;
        }
        hr[0][t] = fmaxf(a0, 0.f);
        hr[1][t] = fmaxf(a1, 0.f);
    }
    __syncthreads();
    int half = t >> 6, oq = t & 63;
    for (int layer = 0; layer < NLh; ++layer) {
        const float* W = Wh + (size_t)layer * Hv * Hv;
        const float* Wp = W + (size_t)(half * 64) * Hv + oq * 4;
        floatx4 a0r0 = {0.f,0.f,0.f,0.f}, a1r0 = {0.f,0.f,0.f,0.f};
        floatx4 a0r1 = {0.f,0.f,0.f,0.f}, a1r1 = {0.f,0.f,0.f,0.f};
        #pragma unroll 8
        for (int kk = 0; kk < 64; kk += 2) {
            floatx4 w0 = *reinterpret_cast<const floatx4*>(Wp + (size_t)kk * Hv);
            floatx4 w1 = *reinterpret_cast<const floatx4*>(Wp + (size_t)(kk+1) * Hv);
            float h00 = hr[0][half*64 + kk], h01 = hr[0][half*64 + kk + 1];
            float h10 = hr[1][half*64 + kk], h11 = hr[1][half*64 + kk + 1];
            a0r0 += w0 * h00; a1r0 += w1 * h01;
            a0r1 += w0 * h10; a1r1 += w1 * h11;
        }
        floatx4 r0 = a0r0 + a1r0, r1 = a0r1 + a1r1;
        *reinterpret_cast<floatx4*>(&part[half][0][oq*4]) = r0;
        *reinterpret_cast<floatx4*>(&part[half][1][oq*4]) = r1;
        __syncthreads();
        int r = t >> 7, o2 = (t & 127) * 2;
        const float* bias = bh + layer * Hv;
        float s0 = part[0][r][o2]   + part[1][r][o2]   + part[2][r][o2]   + part[3][r][o2]   + bias[o2];
        float s1 = part[0][r][o2+1] + part[1][r][o2+1] + part[2][r][o2+1] + part[3][r][o2+1] + bias[o2+1];
        s0 = fmaxf(s0, 0.f); s1 = fmaxf(s1, 0.f);
        if (layer == NLh - 1) {
            *reinterpret_cast<unsigned int*>(
                feat + (size_t)(bq*2 + r) * Pv + net*Hv + o2) = cvt_pk_bf16(s0, s1);
        } else {
            hr[r][o2] = s0; hr[r][o2+1] = s1;
        }
        __syncthreads();
    }
}

// ---------------- Prism helpers ----------------

// 16B global->LDS DMA (zero VGPR round-trip). lds dest = base + lane*16 (auto).
__device__ __forceinline__ void dma16(const float* g, char* lds) {
    __builtin_amdgcn_global_load_lds(
        (const __attribute__((address_space(1))) unsigned int*)g,
        (__attribute__((address_space(3))) unsigned int*)lds, 16, 0, 0);
}

// DMA one 32x256 fp32 W-chunk into buf, linear rows, col-swizzled SOURCE:
// lds[k][o'] = W[k][o' ^ perm(k)], perm(k) = ((k>>3)&3)<<3  (bits 3-4 of o)
__device__ __forceinline__ void dma_chunk(const float* csrc, char* buf, int w, int l) {
    #pragma unroll
    for (int i = 0; i < 4; ++i) {
        int k = w * 4 + i;                       // k-row 0..31 (8 waves x 4)
        int perm = ((k >> 3) & 3) << 3;
        dma16(csrc + (size_t)k * Hv + ((l * 4) ^ perm), buf + k * 1024);
    }
}

// B-fragment: 8 fp32 column reads (swizzled -> 2-way banks) + 4 cvt_pk -> bf16 x8
__device__ __forceinline__ shortx8 bfrag(const char* buf, int o, int l) {
    const int kb = (l >> 4) * 8;
    const int col = o ^ (((l >> 4) & 3) << 3);
    const char* p = buf + kb * 1024 + col * 4;
    float a0 = *(const float*)(p + 0*1024);
    float a1 = *(const float*)(p + 1*1024);
    float a2 = *(const float*)(p + 2*1024);
    float a3 = *(const float*)(p + 3*1024);
    float a4 = *(const float*)(p + 4*1024);
    float a5 = *(const float*)(p + 5*1024);
    float a6 = *(const float*)(p + 6*1024);
    float a7 = *(const float*)(p + 7*1024);
    uintx4 v = { cvt_pk_bf16(a0, a1), cvt_pk_bf16(a2, a3),
                 cvt_pk_bf16(a4, a5), cvt_pk_bf16(a6, a7) };
    shortx8 r;
    __builtin_memcpy(&r, &v, 16);
    return r;
}

// A-fragments for L1 chunk u: 4 x global_load_dwordx4 from feat (L2-resident)
__device__ __forceinline__ void stage_af(const unsigned short* __restrict__ feat,
                                         int u, int wm, int l, shortx8* a) {
    #pragma unroll
    for (int m = 0; m < 4; ++m) {
        int row = wm*64 + m*16 + (l & 15);
        a[m] = *reinterpret_cast<const shortx8*>(
            feat + (size_t)row * Pv + u*CH + ((l >> 4) & 3) * 8);
    }
}

// ---------------- Prism: W via global_load_lds (fp32 in LDS), ring-3 ----------------
// Stream = 24 chunks of 32 k-rows (16 W1 + 8 W2). Per iter u: [A(u+1) loads]
// [DMA W(u+2)] [mfma chunk u] [vmcnt(4)+lgkm+barrier]. vmcnt(4) retires
// A(u+1)+W(u+1), leaves W(u+2)'s 4 DMA ops in flight -> continuous HBM
// pressure, zero prefetch VGPRs, no write-back VALU.

__global__ __launch_bounds__(512, 1) void prism_kernel(
    const unsigned short* __restrict__ feat,
    const float* __restrict__ W1, const float* __restrict__ b1,
    const float* __restrict__ W2, const float* __restrict__ b2,
    const float* __restrict__ W3, const float* __restrict__ b3,
    float* __restrict__ out)
{
    __shared__ __align__(16) char smem[163840];
    char* wb0 = smem;                  // fp32 W chunk bufs, ring-3
    char* wb1 = smem + 32768;
    char* wb2 = smem + 65536;
    char* h1  = smem + 98304;          // 64KB bf16 [128][256] swizzled
    float* subws = (float*)(smem + 98304);  // alias h1; h1 dead at L3

    const int tid = threadIdx.x;
    const int l = tid & 63;
    const int w = tid >> 6;
    const int wm = w >> 2, wn = w & 3;
    const int c = blockIdx.x;
    const float* W1c = W1 + (size_t)c * (Pv * Hv);
    const float* W2c = W2 + (size_t)c * (Hv * Hv);

    shortx8 arr0[4], arr1[4];

    // ---- prologue: A0, W0, A1, W1, W2 (issue order = vmcnt order) ----
    stage_af(feat, 0, wm, l, arr0);
    __builtin_amdgcn_sched_barrier(0);
    dma_chunk(W1c, wb0, w, l);
    __builtin_amdgcn_sched_barrier(0);
    stage_af(feat, 1, wm, l, arr1);
    __builtin_amdgcn_sched_barrier(0);
    dma_chunk(W1c + (size_t)1 * CH * Hv, wb1, w, l);
    dma_chunk(W1c + (size_t)2 * CH * Hv, wb2, w, l);
    asm volatile("s_waitcnt vmcnt(12)" ::: "memory");   // A0+W0 done; A1,W1,W2 fly
    __builtin_amdgcn_sched_barrier(0);
    __builtin_amdgcn_s_barrier();

    floatx4 acc[4][4];
    #pragma unroll
    for (int m = 0; m < 4; ++m)
        #pragma unroll
        for (int n = 0; n < 4; ++n)
            acc[m][n] = (floatx4){0.f, 0.f, 0.f, 0.f};

    // ---- L1: chunks 0..15 ----
    #pragma unroll
    for (int u = 0; u < 16; ++u) {
        if (u >= 1 && u + 1 < 16)
            stage_af(feat, u + 1, wm, l, ((u + 1) & 1) ? arr1 : arr0);
        __builtin_amdgcn_sched_barrier(0);
        if (u >= 1) {
            const float* ps = (u + 2 < 16) ? W1c + (size_t)(u + 2) * CH * Hv
                                           : W2c + (size_t)(u + 2 - 16) * CH * Hv;
            char* dst = ((u + 2) % 3 == 0) ? wb0 : ((u + 2) % 3 == 1) ? wb1 : wb2;
            dma_chunk(ps, dst, w, l);
        }
        __builtin_amdgcn_sched_barrier(0);
        {
            const char* buf = (u % 3 == 0) ? wb0 : (u % 3 == 1) ? wb1 : wb2;
            const shortx8* ac = (u & 1) ? arr1 : arr0;
            #pragma unroll
            for (int n = 0; n < 4; ++n) {
                int o = wn*64 + n*16 + (l & 15);
                shortx8 bf = bfrag(buf, o, l);
                #pragma unroll
                for (int m = 0; m < 4; ++m)
                    acc[m][n] = __builtin_amdgcn_mfma_f32_16x16x32_bf16(ac[m], bf, acc[m][n], 0, 0, 0);
            }
        }
        asm volatile("s_waitcnt vmcnt(4) lgkmcnt(0)" ::: "memory");
        __builtin_amdgcn_sched_barrier(0);
        __builtin_amdgcn_s_barrier();
    }

    // ---- h1 epilogue: relu(acc+b1) -> LDS bf16 swizzled (W(17) DMA stays in flight) ----
    {
        float bias1v[4];
        #pragma unroll
        for (int n = 0; n < 4; ++n)
            bias1v[n] = b1[c*Hv + wn*64 + n*16 + (l & 15)];
        #pragma unroll
        for (int m = 0; m < 4; ++m) {
            #pragma unroll
            for (int n = 0; n < 4; ++n) {
                int o = wn*64 + n*16 + (l & 15);
                #pragma unroll
                for (int jj = 0; jj < 4; ++jj) {
                    int bb = wm*64 + m*16 + (l >> 4)*4 + jj;
                    float v = fmaxf(acc[m][n][jj] + bias1v[n], 0.f);
                    *(unsigned short*)(h1 + bb*512 + ((o*2) ^ (swz(bb) << 4))) =
                        (unsigned short)(cvt_pk_bf16(v, v) & 0xffffu);
                }
            }
        }
    }
    asm volatile("s_waitcnt lgkmcnt(0)" ::: "memory");
    __builtin_amdgcn_s_barrier();

    #pragma unroll
    for (int m = 0; m < 4; ++m)
        #pragma unroll
        for (int n = 0; n < 4; ++n)
            acc[m][n] = (floatx4){0.f, 0.f, 0.f, 0.f};

    // ---- L2: chunks 16..23 (A from h1) ----
    #pragma unroll
    for (int u = 16; u < 24; ++u) {
        if (u + 2 < 24) {
            char* dst = ((u + 2) % 3 == 0) ? wb0 : ((u + 2) % 3 == 1) ? wb1 : wb2;
            dma_chunk(W2c + (size_t)(u + 2 - 16) * CH * Hv, dst, w, l);
        }
        __builtin_amdgcn_sched_barrier(0);
        {
            const char* buf = (u % 3 == 0) ? wb0 : (u % 3 == 1) ? wb1 : wb2;
            int k2 = (u - 16) * CH + (l >> 4) * 8;
            shortx8 af[4];
            #pragma unroll
            for (int m = 0; m < 4; ++m) {
                int row = wm*64 + m*16 + (l & 15);
                af[m] = *reinterpret_cast<const shortx8*>(
                    h1 + row*512 + ((k2*2) ^ (swz(row) << 4)));
            }
            #pragma unroll
            for (int n = 0; n < 4; ++n) {
                int o = wn*64 + n*16 + (l & 15);
                shortx8 bf = bfrag(buf, o, l);
                #pragma unroll
                for (int m = 0; m < 4; ++m)
                    acc[m][n] = __builtin_amdgcn_mfma_f32_16x16x32_bf16(af[m], bf, acc[m][n], 0, 0, 0);
            }
        }
        if (u < 22) asm volatile("s_waitcnt vmcnt(4) lgkmcnt(0)" ::: "memory");
        else        asm volatile("s_waitcnt vmcnt(0) lgkmcnt(0)" ::: "memory");
        __builtin_amdgcn_sched_barrier(0);
        __builtin_amdgcn_s_barrier();
    }

    // ---- L3: sub = relu(h2)·W3 + b3 ----
    float bias2v[4], w3v[4];
    #pragma unroll
    for (int n = 0; n < 4; ++n) {
        int o = wn*64 + n*16 + (l & 15);
        bias2v[n] = b2[c*Hv + o];
        w3v[n]    = W3[c*Hv + o];
    }
    float b3v = b3[c];
    float p[4][4];
    #pragma unroll
    for (int m = 0; m < 4; ++m)
        #pragma unroll
        for (int jj = 0; jj < 4; ++jj) {
            float s = 0.f;
            #pragma unroll
            for (int n = 0; n < 4; ++n)
                s += fmaxf(acc[m][n][jj] + bias2v[n], 0.f) * w3v[n];
            p[m][jj] = s;
        }
    #pragma unroll
    for (int m = 0; m < 4; ++m)
        #pragma unroll
        for (int jj = 0; jj < 4; ++jj) {
            p[m][jj] += __shfl_xor(p[m][jj], 1, 64);
            p[m][jj] += __shfl_xor(p[m][jj], 2, 64);
            p[m][jj] += __shfl_xor(p[m][jj], 4, 64);
            p[m][jj] += __shfl_xor(p[m][jj], 8, 64);
        }
    {
        int t16 = l & 15;
        float pv = 0.f;
        #pragma unroll
        for (int m = 0; m < 4; ++m)
            #pragma unroll
            for (int jj = 0; jj < 4; ++jj)
                if (m == (t16 >> 2) && jj == (t16 & 3)) pv = p[m][jj];
        int bb = wm*64 + (t16 >> 2)*16 + (l >> 4)*4 + (t16 & 3);
        subws[wn*128 + bb] = pv;
    }
    asm volatile("s_waitcnt lgkmcnt(0)" ::: "memory");
    __builtin_amdgcn_s_barrier();
    if (tid < 128) {
        float s = subws[tid] + subws[128 + tid] + subws[256 + tid] + subws[384 + tid] + b3v;
        out[(size_t)tid * Cv + c] = s;
    }
}

// ---------------- mimo epilogue ----------------

__global__ __launch_bounds__(256) void mimo_kernel(
    const float* __restrict__ sub, const float* __restrict__ mW,
    const float* __restrict__ mB, float* __restrict__ out)
{
    int b = blockIdx.x;
    int t = threadIdx.x;
    float s = 0.f;
    #pragma unroll
    for (int j = 0; j < 4; ++j) s += sub[b*Cv + t + j*256];
    #pragma unroll
    for (int m = 1; m < 64; m <<= 1) s += __shfl_xor(s, m, 64);
    __shared__ float red[4];
    if ((t & 63) == 0) red[t >> 6] = s;
    __syncthreads();
    if (t < 8) {
        float mean = (red[0] + red[1] + red[2] + red[3]) * (1.0f / 1024.0f);
        out[Bv * Cv + b*8 + t] = mean * mW[t] + mB[t];
    }
}

// ---------------- launch ----------------

extern "C" void kernel_launch(void* const* d_in, const int* in_sizes, int n_in,
                              void* d_out, int out_size, void* d_ws, size_t ws_size,
                              hipStream_t stream) {
    (void)in_sizes; (void)n_in; (void)out_size; (void)ws_size;
    const float* pos   = (const float*)d_in[0];
    const float* ue    = (const float*)d_in[1];
    const float* bsant = (const float*)d_in[2];
    const float* addf  = (const float*)d_in[3];
    const float* attW1 = (const float*)d_in[4];
    const float* attb1 = (const float*)d_in[5];
    const float* attWh = (const float*)d_in[6];
    const float* attbh = (const float*)d_in[7];
    const float* radW1 = (const float*)d_in[8];
    const float* radb1 = (const float*)d_in[9];
    const float* radWh = (const float*)d_in[10];
    const float* radbh = (const float*)d_in[11];
    const float* pW1   = (const float*)d_in[12];
    const float* pb1   = (const float*)d_in[13];
    const float* pW2   = (const float*)d_in[14];
    const float* pb2   = (const float*)d_in[15];
    const float* pW3   = (const float*)d_in[16];
    const float* pb3   = (const float*)d_in[17];
    const float* mW    = (const float*)d_in[18];
    const float* mB    = (const float*)d_in[19];
    float* out = (float*)d_out;

    unsigned short* feat = (unsigned short*)d_ws;   // [128][512] bf16

    mlp_fused<<<128, 256, 0, stream>>>(pos, ue, bsant, addf,
                                       attW1, attb1, attWh, attbh,
                                       radW1, radb1, radWh, radbh, feat);
    prism_kernel<<<Cv, 512, 0, stream>>>(feat, pW1, pb1, pW2, pb2, pW3, pb3, out);
    mimo_kernel<<<Bv, 256, 0, stream>>>(out, mW, mB, out);
}